// Round 1
// baseline (232.506 us; speedup 1.0000x reference)
//
#include <hip/hip_runtime.h>
#include <hip/hip_bf16.h>
#include <stdint.h>
#include <stddef.h>

// Problem: z[8192,512] f32, mu[1000,8,512] f32
// out = concat(logits[8192,1000], min_dist_sq[8192,1000]) f32
#define B_ROWS 8192
#define C_CLS  1000
#define NPROTO 8000   // C*P
#define D_DIM  512

#define BM 128
#define BN 128
#define BK 64
#define MT (B_ROWS / BM)                 // 64
#define NT ((NPROTO + BN - 1) / BN)      // 63 (last tile partial: protos 7936..8063 -> clamp/guard)

typedef __bf16 bf16x8 __attribute__((ext_vector_type(8)));
typedef float  f32x4  __attribute__((ext_vector_type(4)));

#define AS1 __attribute__((address_space(1)))
#define AS3 __attribute__((address_space(3)))

__device__ __forceinline__ void gload_lds16(const void* g, void* l) {
  // async global->LDS, 16B per lane. LDS dest must be wave-uniform base + lane*16 (it is, see stage()).
  __builtin_amdgcn_global_load_lds((const AS1 uint32_t*)g, (AS3 uint32_t*)l, 16, 0, 0);
}

// ---------- prep: fp32 -> bf16 cast + row sum-of-squares (one wave per row) ----------
__global__ void prep_rows(const float* __restrict__ src, __bf16* __restrict__ dst,
                          float* __restrict__ sq) {
  const int row = blockIdx.x;
  const int l = threadIdx.x;             // 0..63
  const float4* s4 = (const float4*)(src + (size_t)row * D_DIM);
  float4 v0 = s4[l * 2], v1 = s4[l * 2 + 1];
  float ss = v0.x * v0.x + v0.y * v0.y + v0.z * v0.z + v0.w * v0.w
           + v1.x * v1.x + v1.y * v1.y + v1.z * v1.z + v1.w * v1.w;
  bf16x8 o;
  o[0] = (__bf16)v0.x; o[1] = (__bf16)v0.y; o[2] = (__bf16)v0.z; o[3] = (__bf16)v0.w;
  o[4] = (__bf16)v1.x; o[5] = (__bf16)v1.y; o[6] = (__bf16)v1.z; o[7] = (__bf16)v1.w;
  ((bf16x8*)(dst + (size_t)row * D_DIM))[l] = o;
  #pragma unroll
  for (int off = 32; off; off >>= 1) ss += __shfl_down(ss, off);
  if (l == 0) sq[row] = ss;
}

// ---------- main fused GEMM + dist + min-over-P ----------
__launch_bounds__(256)
__global__ void proto_gemm(const __bf16* __restrict__ Zb, const __bf16* __restrict__ Mub,
                           const float* __restrict__ Z2, const float* __restrict__ Mu2,
                           float* __restrict__ logits, float* __restrict__ mind) {
  __shared__ __align__(16) __bf16 lds_a[BM * BK];   // [m][k] row-major
  __shared__ __align__(16) __bf16 lds_b[BN * BK];   // [n][k] row-major (mu is already [proto][d])
  __shared__ float z2s[BM];
  __shared__ float mu2s[BN];
  __shared__ float sm[BM * 16];                      // per-block min-dist tile: 128 rows x 16 classes

  const int bid = blockIdx.x;
  const int mt = bid / NT;
  const int nt = bid % NT;
  const int tid = threadIdx.x;
  const int l  = tid & 63;
  const int w  = tid >> 6;       // 4 waves, 2x2 over the 128x128 tile
  const int wm = w >> 1, wn = w & 1;

  if (tid < BM) {
    z2s[tid] = Z2[mt * BM + tid];
  } else {
    const int i = tid - BM;
    const int gn = nt * BN + i;
    mu2s[i] = (gn < NPROTO) ? Mu2[gn] : 0.f;
  }

  // staging geometry: chunk = i*256 + tid (i=0..3); row = chunk>>3, k-offset = (tid&7)*8 elems.
  // LDS byte offset = chunk*16 -> per wave: uniform base + lane*16 (required by global_load_lds).
  const int kofs = (tid & 7) * 8;
  const int r0   = tid >> 3;     // 0..31
  const __bf16* gAb = Zb + ((size_t)(mt * BM + r0)) * D_DIM + kofs;
  const __bf16* gBb[4];
  #pragma unroll
  for (int i = 0; i < 4; ++i) {
    int rn = nt * BN + i * 32 + r0;
    if (rn > NPROTO - 1) rn = NPROTO - 1;   // clamp OOB proto rows (their classes are write-guarded)
    gBb[i] = Mub + (size_t)rn * D_DIM + kofs;
  }

  f32x4 acc[4][4];
  const f32x4 fzero = {0.f, 0.f, 0.f, 0.f};
  #pragma unroll
  for (int i = 0; i < 4; ++i)
    #pragma unroll
    for (int j = 0; j < 4; ++j) acc[i][j] = fzero;

  #define STAGE(kt)                                                            \
    do {                                                                       \
      const int kb_ = (kt) * BK;                                               \
      _Pragma("unroll")                                                        \
      for (int i_ = 0; i_ < 4; ++i_) {                                         \
        gload_lds16(gAb + (size_t)i_ * 32 * D_DIM + kb_,                       \
                    &lds_a[(i_ * 256 + tid) * 8]);                             \
        gload_lds16(gBb[i_] + kb_, &lds_b[(i_ * 256 + tid) * 8]);              \
      }                                                                        \
    } while (0)

  STAGE(0);
  for (int kt = 0; kt < D_DIM / BK; ++kt) {
    __syncthreads();   // compiler drains vmcnt(0) here -> staged tile visible
    #pragma unroll
    for (int ks = 0; ks < 2; ++ks) {
      bf16x8 af[4], bf[4];
      const int ko = ks * 32 + (l >> 4) * 8;
      #pragma unroll
      for (int i = 0; i < 4; ++i)
        af[i] = *(const bf16x8*)&lds_a[(wm * 64 + i * 16 + (l & 15)) * BK + ko];
      #pragma unroll
      for (int j = 0; j < 4; ++j)
        bf[j] = *(const bf16x8*)&lds_b[(wn * 64 + j * 16 + (l & 15)) * BK + ko];
      #pragma unroll
      for (int i = 0; i < 4; ++i)
        #pragma unroll
        for (int j = 0; j < 4; ++j)
          acc[i][j] = __builtin_amdgcn_mfma_f32_16x16x32_bf16(af[i], bf[j], acc[i][j], 0, 0, 0);
    }
    __syncthreads();   // all waves done reading before next-tile overwrite
    if (kt + 1 < D_DIM / BK) STAGE(kt + 1);
  }

  // epilogue: dist = z2 + mu2 - 2*cross; min over 8 consecutive protos (= lane bits 0..2 of col)
  // C/D layout (m89/m91-verified): col = lane&15, row = (lane>>4)*4 + reg
  const int c16 = l & 15;
  const int rq  = l >> 4;
  #pragma unroll
  for (int j = 0; j < 4; ++j) {
    const float m2 = mu2s[wn * 64 + j * 16 + c16];
    #pragma unroll
    for (int i = 0; i < 4; ++i) {
      const int rb = wm * 64 + i * 16 + rq * 4;
      float d0 = fmaf(-2.f, acc[i][j][0], z2s[rb + 0] + m2);
      float d1 = fmaf(-2.f, acc[i][j][1], z2s[rb + 1] + m2);
      float d2 = fmaf(-2.f, acc[i][j][2], z2s[rb + 2] + m2);
      float d3 = fmaf(-2.f, acc[i][j][3], z2s[rb + 3] + m2);
      #pragma unroll
      for (int mk = 1; mk < 8; mk <<= 1) {
        d0 = fminf(d0, __shfl_xor(d0, mk));
        d1 = fminf(d1, __shfl_xor(d1, mk));
        d2 = fminf(d2, __shfl_xor(d2, mk));
        d3 = fminf(d3, __shfl_xor(d3, mk));
      }
      if ((l & 7) == 0) {
        const int cl = (wn * 64 + j * 16 + c16) >> 3;   // 0..15 class within tile
        sm[(rb + 0) * 16 + cl] = d0;
        sm[(rb + 1) * 16 + cl] = d1;
        sm[(rb + 2) * 16 + cl] = d2;
        sm[(rb + 3) * 16 + cl] = d3;
      }
    }
  }
  __syncthreads();

  // coalesced float4 write of both outputs (class quad either fully valid or fully OOB: 1000%4==0)
  const int cb = nt * 16;
  for (int idx = tid; idx < BM * 4; idx += 256) {
    const int row = idx >> 2, q = idx & 3;
    if (cb + q * 4 < C_CLS) {
      f32x4 v = *(const f32x4*)&sm[row * 16 + q * 4];
      const size_t o = (size_t)(mt * BM + row) * C_CLS + cb + q * 4;
      *(f32x4*)&mind[o] = v;
      f32x4 nv = -v;
      *(f32x4*)&logits[o] = nv;
    }
  }
}

// ---------- fallback (fp32, no workspace) in case ws_size is too small ----------
__global__ void fallback_kernel(const float* __restrict__ z, const float* __restrict__ mu,
                                float* __restrict__ logits, float* __restrict__ mind) {
  const int b = blockIdx.x;
  const int w = threadIdx.x >> 6, l = threadIdx.x & 63;
  const int c = blockIdx.y * 4 + w;
  const float* zr = z + (size_t)b * D_DIM;
  float best = 3.4e38f;
  for (int p = 0; p < 8; ++p) {
    const float* m = mu + ((size_t)c * 8 + p) * D_DIM;
    float s = 0.f;
    for (int d = l; d < D_DIM; d += 64) {
      float df = zr[d] - m[d];
      s = fmaf(df, df, s);
    }
    #pragma unroll
    for (int off = 32; off; off >>= 1) s += __shfl_down(s, off);
    s = __shfl(s, 0);
    best = fminf(best, s);
  }
  if (l == 0) {
    logits[(size_t)b * C_CLS + c] = -best;
    mind[(size_t)b * C_CLS + c] = best;
  }
}

extern "C" void kernel_launch(void* const* d_in, const int* in_sizes, int n_in,
                              void* d_out, int out_size, void* d_ws, size_t ws_size,
                              hipStream_t stream) {
  const float* z  = (const float*)d_in[0];
  const float* mu = (const float*)d_in[1];
  float* logits = (float*)d_out;
  float* mind   = logits + (size_t)B_ROWS * C_CLS;

  const size_t zb_bytes  = (size_t)B_ROWS * D_DIM * 2;
  const size_t mub_bytes = (size_t)NPROTO * D_DIM * 2;
  const size_t need = zb_bytes + mub_bytes + (size_t)B_ROWS * 4 + (size_t)NPROTO * 4;

  if (ws_size >= need) {
    char* p = (char*)d_ws;
    __bf16* zb  = (__bf16*)p; p += zb_bytes;
    __bf16* mub = (__bf16*)p; p += mub_bytes;
    float* z2   = (float*)p;  p += (size_t)B_ROWS * 4;
    float* mu2  = (float*)p;
    prep_rows<<<B_ROWS, 64, 0, stream>>>(z, zb, z2);
    prep_rows<<<NPROTO, 64, 0, stream>>>(mu, mub, mu2);
    proto_gemm<<<MT * NT, 256, 0, stream>>>(zb, mub, z2, mu2, logits, mind);
  } else {
    dim3 g(B_ROWS, C_CLS / 4);
    fallback_kernel<<<g, 256, 0, stream>>>(z, mu, logits, mind);
  }
}

// Round 2
// 194.197 us; speedup vs baseline: 1.1973x; 1.1973x over previous
//
#include <hip/hip_runtime.h>
#include <hip/hip_bf16.h>
#include <stdint.h>
#include <stddef.h>

// z[8192,512] f32, mu[1000,8,512] f32 -> out = concat(logits[8192,1000], min_dist_sq[8192,1000]) f32
#define B_ROWS 8192
#define C_CLS  1000
#define NPROTO 8000
#define D_DIM  512

#define TM 256
#define TN 256
#define TK 64
#define MT 32                 // 8192/256
#define NT 32                 // ceil(8000/256), last tile 64 valid proto rows

typedef __bf16 bf16x8 __attribute__((ext_vector_type(8)));
typedef float  f32x4  __attribute__((ext_vector_type(4)));

#define AS1 __attribute__((address_space(1)))
#define AS3 __attribute__((address_space(3)))

__device__ __forceinline__ void gload_lds16(const void* g, void* l) {
  // async global->LDS, 16B/lane, LDS dest = wave-uniform base + lane*16 (linear).
  __builtin_amdgcn_global_load_lds((const AS1 uint32_t*)g, (AS3 uint32_t*)l, 16, 0, 0);
}

// LDS map (bytes): buf0: A 0..32K, B 32K..64K; buf1: A 64K..96K, B 96K..128K; z2s/mu2s after.
#define ABUF(d) ((d) * 65536)
#define BBUF(d) ((d) * 65536 + 32768)
#define Z2OFF   131072
#define MU2OFF  132096
#define LDS_BYTES 133120

// ---------- prep: fp32 -> bf16 cast + row sum-of-squares; z rows then mu rows ----------
__global__ void prep_rows(const float* __restrict__ z, const float* __restrict__ mu,
                          __bf16* __restrict__ zb, __bf16* __restrict__ mub,
                          float* __restrict__ z2, float* __restrict__ mu2) {
  const int r = blockIdx.x * 4 + (threadIdx.x >> 6);
  const int l = threadIdx.x & 63;
  const float* src; __bf16* dst; float* sq; int row;
  if (r < B_ROWS) { src = z;  dst = zb;  sq = z2;  row = r; }
  else            { src = mu; dst = mub; sq = mu2; row = r - B_ROWS; }
  const float4* s4 = (const float4*)(src + (size_t)row * D_DIM);
  float4 v0 = s4[l * 2], v1 = s4[l * 2 + 1];
  float ss = v0.x * v0.x + v0.y * v0.y + v0.z * v0.z + v0.w * v0.w
           + v1.x * v1.x + v1.y * v1.y + v1.z * v1.z + v1.w * v1.w;
  bf16x8 o;
  o[0] = (__bf16)v0.x; o[1] = (__bf16)v0.y; o[2] = (__bf16)v0.z; o[3] = (__bf16)v0.w;
  o[4] = (__bf16)v1.x; o[5] = (__bf16)v1.y; o[6] = (__bf16)v1.z; o[7] = (__bf16)v1.w;
  ((bf16x8*)(dst + (size_t)row * D_DIM))[l] = o;
  #pragma unroll
  for (int off = 32; off; off >>= 1) ss += __shfl_down(ss, off);
  if (l == 0) sq[row] = ss;
}

// ---------- main fused GEMM + dist + min-over-P: 256x256 tile, 8 waves, counted-vmcnt pipeline ----------
__launch_bounds__(512, 2)
__global__ void proto_gemm(const __bf16* __restrict__ Zb, const __bf16* __restrict__ Mub,
                           const float* __restrict__ Z2, const float* __restrict__ Mu2,
                           float* __restrict__ logits, float* __restrict__ mind) {
  __shared__ __align__(16) unsigned char smem[LDS_BYTES];

  const int tid = threadIdx.x;
  const int l   = tid & 63;
  const int w   = tid >> 6;      // 8 waves: 2 (M) x 4 (N)
  const int wm  = w >> 2;        // 0..1  -> rows wm*128..+127
  const int wn  = w & 3;         // 0..3  -> cols wn*64..+63

  // T1: XCD chunking (grid 1024 = 8 XCDs x 128; chunk = 16 mt x 8 nt; within chunk nt fastest)
  const int xcd = blockIdx.x & 7, cc = blockIdx.x >> 3;
  const int mt = (xcd & 1) * 16 + (cc >> 3);
  const int nt = (xcd >> 1) * 8 + (cc & 7);

  float* z2s  = (float*)(smem + Z2OFF);
  float* mu2s = (float*)(smem + MU2OFF);
  if (tid < 256) {
    z2s[tid] = Z2[mt * 256 + tid];
  } else {
    const int i = tid - 256;
    const int gn = nt * 256 + i;
    mu2s[i] = Mu2[gn < NPROTO ? gn : NPROTO - 1];
  }

  // ---- staging geometry (T2 both-sides swizzle, rule #21): linear LDS dest,
  // inverse-swizzled global source. LDS byte o holds element at lin = o ^ ((o>>7&7)<<4):
  // row = o>>7 (XOR leaves rows), col elems = ((o&127)^((o>>7&7)<<4))/2.
  const int sr   = tid >> 3;                                  // row within 64-row chunk
  const int scol = ((tid & 7) * 8) ^ ((sr & 7) * 8);          // pre-swizzled element col
  const __bf16* pA[4]; const __bf16* pB[4];
  #pragma unroll
  for (int q = 0; q < 4; ++q) {
    pA[q] = Zb + (size_t)(mt * 256 + q * 64 + sr) * D_DIM + scol;
    int rb = nt * 256 + q * 64 + sr;
    if (rb > NPROTO - 1) rb = NPROTO - 1;                     // OOB protos clamped (classes write-guarded)
    pB[q] = Mub + (size_t)rb * D_DIM + scol;
  }
  const int ldst = tid * 16;

  #define STAGE(T, D)                                                        \
    {                                                                        \
      _Pragma("unroll")                                                      \
      for (int q = 0; q < 4; ++q)                                            \
        gload_lds16(pA[q] + (T) * TK, smem + ABUF(D) + q * 8192 + ldst);     \
      _Pragma("unroll")                                                      \
      for (int q = 0; q < 4; ++q)                                            \
        gload_lds16(pB[q] + (T) * TK, smem + BBUF(D) + q * 8192 + ldst);     \
    }

  STAGE(0, 0);   // 8 per-wave loads
  STAGE(1, 1);   // 8 more -> vmcnt 16 outstanding

  // ---- reader offsets (swizzled): frag(i,ks): row = base + i*16 + (l&15), k = ks*32+(l>>4)*8
  // byte = row*128 + ks*64 + (l>>4)*16, then ^ ((row&7)<<4); row&7 == l&7 here.
  const int lx = (l & 7) << 4;
  const int lane_lin = (l & 15) * 128 + (l >> 4) * 16;
  const int ok0 = lane_lin ^ lx;
  const int ok1 = (lane_lin + 64) ^ lx;
  const int abase_w = wm * 16384;   // wm*128 rows * 128 B
  const int bbase_w = wn * 8192;    // wn*64 rows * 128 B

  f32x4 acc[8][4];
  #pragma unroll
  for (int i = 0; i < 8; ++i)
    #pragma unroll
    for (int j = 0; j < 4; ++j) acc[i][j] = (f32x4){0.f, 0.f, 0.f, 0.f};

  // One K-tile per iteration. Counted vmcnt(8) (next tile's loads stay in flight across
  // the barrier); lgkmcnt(0)+barrier = all waves done READING buf[d] before re-staging it.
  #define KITER(T, VMS, DOSTAGE)                                                         \
  {                                                                                      \
    constexpr int d_ = (T) & 1;                                                          \
    asm volatile("s_waitcnt vmcnt(" VMS ")" ::: "memory");                               \
    __builtin_amdgcn_s_barrier();                                                        \
    bf16x8 af[8], bb[4];                                                                 \
    _Pragma("unroll")                                                                    \
    for (int i = 0; i < 8; ++i)                                                          \
      af[i] = *(const bf16x8*)(smem + ABUF(d_) + abase_w + i * 2048 + ok0);              \
    _Pragma("unroll")                                                                    \
    for (int j = 0; j < 4; ++j)                                                          \
      bb[j] = *(const bf16x8*)(smem + BBUF(d_) + bbase_w + j * 2048 + ok0);              \
    __builtin_amdgcn_s_setprio(1);                                                       \
    _Pragma("unroll")                                                                    \
    for (int i = 0; i < 8; ++i)                                                          \
      _Pragma("unroll")                                                                  \
      for (int j = 0; j < 4; ++j)                                                        \
        acc[i][j] = __builtin_amdgcn_mfma_f32_16x16x32_bf16(af[i], bb[j], acc[i][j], 0, 0, 0); \
    __builtin_amdgcn_s_setprio(0);                                                       \
    _Pragma("unroll")                                                                    \
    for (int i = 0; i < 8; ++i)                                                          \
      af[i] = *(const bf16x8*)(smem + ABUF(d_) + abase_w + i * 2048 + ok1);              \
    _Pragma("unroll")                                                                    \
    for (int j = 0; j < 4; ++j)                                                          \
      bb[j] = *(const bf16x8*)(smem + BBUF(d_) + bbase_w + j * 2048 + ok1);              \
    asm volatile("s_waitcnt lgkmcnt(0)" ::: "memory");                                   \
    __builtin_amdgcn_s_barrier();                                                        \
    if (DOSTAGE) STAGE((T) + 2, d_);                                                     \
    __builtin_amdgcn_s_setprio(1);                                                       \
    _Pragma("unroll")                                                                    \
    for (int i = 0; i < 8; ++i)                                                          \
      _Pragma("unroll")                                                                  \
      for (int j = 0; j < 4; ++j)                                                        \
        acc[i][j] = __builtin_amdgcn_mfma_f32_16x16x32_bf16(af[i], bb[j], acc[i][j], 0, 0, 0); \
    __builtin_amdgcn_s_setprio(0);                                                       \
  }

  KITER(0, "8", true)
  KITER(1, "8", true)
  KITER(2, "8", true)
  KITER(3, "8", true)
  KITER(4, "8", true)
  KITER(5, "8", true)
  KITER(6, "8", false)
  KITER(7, "0", false)

  // ---- epilogue: dist = z2 + mu2 - 2*cross; min over 8 consecutive protos (lane bits 0..2).
  // C/D layout (m89/m91): col = l&15 (proto), row = (l>>4)*4 + reg (z row).
  float* smf = (float*)smem;       // sm[256][32] aliases dead buf0
  const int c16 = l & 15;
  const int rq  = l >> 4;
  #pragma unroll
  for (int j = 0; j < 4; ++j) {
    const float m2 = mu2s[wn * 64 + j * 16 + c16];
    #pragma unroll
    for (int i = 0; i < 8; ++i) {
      const int rb = wm * 128 + i * 16 + rq * 4;
      float d0 = fmaf(-2.f, acc[i][j][0], z2s[rb + 0] + m2);
      float d1 = fmaf(-2.f, acc[i][j][1], z2s[rb + 1] + m2);
      float d2 = fmaf(-2.f, acc[i][j][2], z2s[rb + 2] + m2);
      float d3 = fmaf(-2.f, acc[i][j][3], z2s[rb + 3] + m2);
      #pragma unroll
      for (int mk = 1; mk < 8; mk <<= 1) {
        d0 = fminf(d0, __shfl_xor(d0, mk));
        d1 = fminf(d1, __shfl_xor(d1, mk));
        d2 = fminf(d2, __shfl_xor(d2, mk));
        d3 = fminf(d3, __shfl_xor(d3, mk));
      }
      if ((l & 7) == 0) {
        const int cl = (wn * 64 + j * 16 + c16) >> 3;   // 0..31 class within tile
        smf[(rb + 0) * 32 + cl] = d0;
        smf[(rb + 1) * 32 + cl] = d1;
        smf[(rb + 2) * 32 + cl] = d2;
        smf[(rb + 3) * 32 + cl] = d3;
      }
    }
  }
  __syncthreads();

  // coalesced float4 writes of both outputs (class quads fully valid or fully OOB; 1000%4==0)
  const int cb = nt * 32;
  for (int idx = tid; idx < 256 * 8; idx += 512) {
    const int row = idx >> 3, q = idx & 7;
    const int gc = cb + q * 4;
    if (gc < C_CLS) {
      f32x4 v = *(const f32x4*)&smf[row * 32 + q * 4];
      const size_t o = (size_t)(mt * 256 + row) * C_CLS + gc;
      *(f32x4*)&mind[o] = v;
      f32x4 nv = { -v[0], -v[1], -v[2], -v[3] };
      *(f32x4*)&logits[o] = nv;
    }
  }
}

// ---------- fallback (fp32) in case ws_size is too small ----------
__global__ void fallback_kernel(const float* __restrict__ z, const float* __restrict__ mu,
                                float* __restrict__ logits, float* __restrict__ mind) {
  const int b = blockIdx.x;
  const int w = threadIdx.x >> 6, l = threadIdx.x & 63;
  const int c = blockIdx.y * 4 + w;
  const float* zr = z + (size_t)b * D_DIM;
  float best = 3.4e38f;
  for (int p = 0; p < 8; ++p) {
    const float* m = mu + ((size_t)c * 8 + p) * D_DIM;
    float s = 0.f;
    for (int d = l; d < D_DIM; d += 64) {
      float df = zr[d] - m[d];
      s = fmaf(df, df, s);
    }
    #pragma unroll
    for (int off = 32; off; off >>= 1) s += __shfl_down(s, off);
    s = __shfl(s, 0);
    best = fminf(best, s);
  }
  if (l == 0) {
    logits[(size_t)b * C_CLS + c] = -best;
    mind[(size_t)b * C_CLS + c] = best;
  }
}

extern "C" void kernel_launch(void* const* d_in, const int* in_sizes, int n_in,
                              void* d_out, int out_size, void* d_ws, size_t ws_size,
                              hipStream_t stream) {
  const float* z  = (const float*)d_in[0];
  const float* mu = (const float*)d_in[1];
  float* logits = (float*)d_out;
  float* mind   = logits + (size_t)B_ROWS * C_CLS;

  const size_t zb_bytes  = (size_t)B_ROWS * D_DIM * 2;
  const size_t mub_bytes = (size_t)NPROTO * D_DIM * 2;
  const size_t need = zb_bytes + mub_bytes + (size_t)B_ROWS * 4 + (size_t)NPROTO * 4;

  if (ws_size >= need) {
    char* p = (char*)d_ws;
    __bf16* zb  = (__bf16*)p; p += zb_bytes;
    __bf16* mub = (__bf16*)p; p += mub_bytes;
    float* z2   = (float*)p;  p += (size_t)B_ROWS * 4;
    float* mu2  = (float*)p;
    prep_rows<<<(B_ROWS + NPROTO) / 4, 256, 0, stream>>>(z, mu, zb, mub, z2, mu2);
    proto_gemm<<<MT * NT, 512, 0, stream>>>(zb, mub, z2, mu2, logits, mind);
  } else {
    dim3 g(B_ROWS, C_CLS / 4);
    fallback_kernel<<<g, 256, 0, stream>>>(z, mu, logits, mind);
  }
}

// Round 3
// 155.304 us; speedup vs baseline: 1.4971x; 1.2504x over previous
//
#include <hip/hip_runtime.h>
#include <hip/hip_bf16.h>
#include <stdint.h>
#include <stddef.h>

// z[8192,512] f32, mu[1000,8,512] f32 -> out = concat(logits[8192,1000], min_dist_sq[8192,1000]) f32
#define B_ROWS 8192
#define C_CLS  1000
#define NPROTO 8000
#define D_DIM  512

#define TK 64
#define MT 32                 // proto tiles (A side): 32*256 = 8192 >= 8000
#define NT 32                 // z tiles (B side): 8192/256

typedef __bf16 bf16x8 __attribute__((ext_vector_type(8)));
typedef float  f32x4  __attribute__((ext_vector_type(4)));

#define AS1 __attribute__((address_space(1)))
#define AS3 __attribute__((address_space(3)))

__device__ __forceinline__ void gload_lds16(const void* g, void* l) {
  __builtin_amdgcn_global_load_lds((const AS1 uint32_t*)g, (AS3 uint32_t*)l, 16, 0, 0);
}

__device__ __forceinline__ f32x4 mfma16(bf16x8 a, bf16x8 b, f32x4 c) {
  return __builtin_amdgcn_mfma_f32_16x16x32_bf16(a, b, c, 0, 0, 0);
}

// LDS map (bytes): buf d: A(mu) at d*65536, B(z) at d*65536+32768; z2s/mu2s above 128K.
#define ABUF(d) ((d) * 65536)
#define BBUF(d) ((d) * 65536 + 32768)
#define Z2OFF   131072
#define MU2OFF  132096
#define LDS_BYTES 133120

// ---------- prep: fp32 -> bf16 cast + row sum-of-squares; z rows then mu rows ----------
__global__ void prep_rows(const float* __restrict__ z, const float* __restrict__ mu,
                          __bf16* __restrict__ zb, __bf16* __restrict__ mub,
                          float* __restrict__ z2, float* __restrict__ mu2) {
  const int r = blockIdx.x * 4 + (threadIdx.x >> 6);
  const int l = threadIdx.x & 63;
  const float* src; __bf16* dst; float* sq; int row;
  if (r < B_ROWS) { src = z;  dst = zb;  sq = z2;  row = r; }
  else            { src = mu; dst = mub; sq = mu2; row = r - B_ROWS; }
  const float4* s4 = (const float4*)(src + (size_t)row * D_DIM);
  float4 v0 = s4[l * 2], v1 = s4[l * 2 + 1];
  float ss = v0.x * v0.x + v0.y * v0.y + v0.z * v0.z + v0.w * v0.w
           + v1.x * v1.x + v1.y * v1.y + v1.z * v1.z + v1.w * v1.w;
  bf16x8 o;
  o[0] = (__bf16)v0.x; o[1] = (__bf16)v0.y; o[2] = (__bf16)v0.z; o[3] = (__bf16)v0.w;
  o[4] = (__bf16)v1.x; o[5] = (__bf16)v1.y; o[6] = (__bf16)v1.z; o[7] = (__bf16)v1.w;
  ((bf16x8*)(dst + (size_t)row * D_DIM))[l] = o;
  #pragma unroll
  for (int off = 32; off; off >>= 1) ss += __shfl_down(ss, off);
  if (l == 0) sq[row] = ss;
}

// ---------- fused GEMM(A=mu, B=z) + dist + min-over-P, phase-interleaved ----------
__launch_bounds__(512, 2)
__global__ void proto_gemm(const __bf16* __restrict__ Zb, const __bf16* __restrict__ Mub,
                           const float* __restrict__ Z2, const float* __restrict__ Mu2,
                           float* __restrict__ logits, float* __restrict__ mind) {
  __shared__ __align__(16) unsigned char smem[LDS_BYTES];

  const int tid = threadIdx.x;
  const int l   = tid & 63;
  const int w   = tid >> 6;      // 8 waves: 2 (proto/M) x 4 (zrow/N)
  const int wm  = w >> 2;        // proto half: rows wm*128..+127
  const int wn  = w & 3;         // z quarter: cols wn*64..+63

  // T1: XCD chunking (1024 blocks = 8 XCDs x 128)
  const int xcd = blockIdx.x & 7, cc = blockIdx.x >> 3;
  const int mt = (xcd & 1) * 16 + (cc >> 3);   // proto tile
  const int nt = (xcd >> 1) * 8 + (cc & 7);    // z tile

  // staging geometry (both-sides swizzle): linear LDS dest, pre-swizzled global col.
  const int sr   = tid >> 3;
  const int scol = ((tid & 7) * 8) ^ ((sr & 7) * 8);
  const __bf16* pA[4]; const __bf16* pB[4];
  #pragma unroll
  for (int q = 0; q < 4; ++q) {
    int rp = mt * 256 + q * 64 + sr;
    if (rp > NPROTO - 1) rp = NPROTO - 1;     // clamp OOB protos (classes write-guarded)
    pA[q] = Mub + (size_t)rp * D_DIM + scol;
    pB[q] = Zb + (size_t)(nt * 256 + q * 64 + sr) * D_DIM + scol;
  }
  const int ldst = tid * 16;

  #define STAGE(T, D)                                                        \
    {                                                                        \
      _Pragma("unroll")                                                      \
      for (int q = 0; q < 4; ++q)                                            \
        gload_lds16(pA[q] + (T) * TK, smem + ABUF(D) + q * 8192 + ldst);     \
      _Pragma("unroll")                                                      \
      for (int q = 0; q < 4; ++q)                                            \
        gload_lds16(pB[q] + (T) * TK, smem + BBUF(D) + q * 8192 + ldst);     \
    }

  STAGE(0, 0);
  STAGE(1, 1);

  float* z2s  = (float*)(smem + Z2OFF);    // z2 for this block's 256 z-rows
  float* mu2s = (float*)(smem + MU2OFF);   // mu2 for this block's 256 protos
  if (tid < 256) {
    z2s[tid] = Z2[nt * 256 + tid];
  } else {
    const int i = tid - 256;
    const int gp = mt * 256 + i;
    mu2s[i] = Mu2[gp < NPROTO ? gp : NPROTO - 1];
  }

  // swizzled reader offsets: frag row = base + (l&15), k-chunk (l>>4)
  const int lx = (l & 7) << 4;
  const int lane_lin = (l & 15) * 128 + (l >> 4) * 16;
  const int ok0 = lane_lin ^ lx;
  const int ok1 = (lane_lin + 64) ^ lx;
  const int abase_w = wm * 16384;   // 128 proto-rows * 128 B
  const int bbase_w = wn * 8192;    // 64 z-rows * 128 B

  f32x4 acc[8][4];
  #pragma unroll
  for (int i = 0; i < 8; ++i)
    #pragma unroll
    for (int j = 0; j < 4; ++j) acc[i][j] = (f32x4){0.f, 0.f, 0.f, 0.f};

  // tile-0 landed (16+2 vmem in flight; >=10 oldest retired covers tile 0)
  asm volatile("s_waitcnt vmcnt(8)" ::: "memory");
  __builtin_amdgcn_s_barrier();

  // Phase-interleaved K-tile: B-frags once, A in 4 pairs, 16-MFMA clusters between reads.
  // Invariant (proven r2): ALL reads of buf d precede the lgkm(0)+barrier that gates STAGE
  // into the same buffer; final MFMA cluster runs on registers and overlaps STAGE issue.
  #define KTILE(T, DOSTAGE, VMEND)                                               \
  {                                                                              \
    constexpr int d_ = (T) & 1;                                                  \
    const unsigned char* ab = smem + ABUF(d_) + abase_w;                         \
    const unsigned char* bp = smem + BBUF(d_) + bbase_w;                         \
    bf16x8 bb0[4], bb1[4];                                                       \
    _Pragma("unroll")                                                            \
    for (int j = 0; j < 4; ++j) {                                                \
      bb0[j] = *(const bf16x8*)(bp + j * 2048 + ok0);                            \
      bb1[j] = *(const bf16x8*)(bp + j * 2048 + ok1);                            \
    }                                                                            \
    _Pragma("unroll")                                                            \
    for (int ip = 0; ip < 4; ++ip) {                                             \
      bf16x8 a0 = *(const bf16x8*)(ab + (2 * ip) * 2048 + ok0);                  \
      bf16x8 a1 = *(const bf16x8*)(ab + (2 * ip) * 2048 + ok1);                  \
      bf16x8 a2 = *(const bf16x8*)(ab + (2 * ip + 1) * 2048 + ok0);              \
      bf16x8 a3 = *(const bf16x8*)(ab + (2 * ip + 1) * 2048 + ok1);              \
      if (ip == 3 && (DOSTAGE)) {                                                \
        asm volatile("s_waitcnt lgkmcnt(0)" ::: "memory");                       \
        __builtin_amdgcn_s_barrier();                                            \
        STAGE((T) + 2, d_);                                                      \
      }                                                                          \
      __builtin_amdgcn_s_setprio(1);                                             \
      _Pragma("unroll")                                                          \
      for (int j = 0; j < 4; ++j) {                                              \
        acc[2 * ip][j]     = mfma16(a0, bb0[j], acc[2 * ip][j]);                 \
        acc[2 * ip][j]     = mfma16(a1, bb1[j], acc[2 * ip][j]);                 \
        acc[2 * ip + 1][j] = mfma16(a2, bb0[j], acc[2 * ip + 1][j]);             \
        acc[2 * ip + 1][j] = mfma16(a3, bb1[j], acc[2 * ip + 1][j]);             \
      }                                                                          \
      __builtin_amdgcn_s_setprio(0);                                             \
    }                                                                            \
    asm volatile("s_waitcnt vmcnt(" VMEND ")" ::: "memory");                     \
    __builtin_amdgcn_s_barrier();                                                \
  }

  KTILE(0, true, "8")
  KTILE(1, true, "8")
  KTILE(2, true, "8")
  KTILE(3, true, "8")
  KTILE(4, true, "8")
  KTILE(5, true, "8")
  KTILE(6, false, "0")
  KTILE(7, false, "0")

  // ---- epilogue. C/D layout: col (l&15) = z-row, row (l>>4)*4+reg = proto.
  // min over 8 protos = min over 4 regs (in-lane) + shfl_xor(16); z2 added at store.
  f32x4 mu2v[8];
  const int rq = l >> 4;
  #pragma unroll
  for (int i = 0; i < 8; ++i)
    mu2v[i] = *(const f32x4*)&mu2s[wm * 128 + i * 16 + rq * 4];

  __syncthreads();                    // all K-loop LDS reads done; reuse buf area
  float* smf = (float*)smem;          // [256 zrows][36] (pad: conflict-free + aligned quads)
  #pragma unroll
  for (int i = 0; i < 8; ++i) {
    const f32x4 m2 = mu2v[i];
    #pragma unroll
    for (int j = 0; j < 4; ++j) {
      const float d0 = fmaf(-2.f, acc[i][j][0], m2[0]);
      const float d1 = fmaf(-2.f, acc[i][j][1], m2[1]);
      const float d2 = fmaf(-2.f, acc[i][j][2], m2[2]);
      const float d3 = fmaf(-2.f, acc[i][j][3], m2[3]);
      float mh = fminf(fminf(d0, d1), fminf(d2, d3));
      float mc = fminf(mh, __shfl_xor(mh, 16));
      if (!(l & 16)) {                // lanes rq in {0,2}: one group per class
        const int zr = wn * 64 + j * 16 + (l & 15);
        const int cl = (wm * 128 + i * 16) / 8 + (l >> 5);
        smf[zr * 36 + cl] = mc;
      }
    }
  }
  __syncthreads();

  const int cb = mt * 32;
  for (int idx = tid; idx < 256 * 8; idx += 512) {
    const int row = idx >> 3, q = idx & 7;
    const int gc = cb + q * 4;
    if (gc < C_CLS) {
      f32x4 v = *(const f32x4*)&smf[row * 36 + q * 4];
      const float zz = z2s[row];
      f32x4 ov = { v[0] + zz, v[1] + zz, v[2] + zz, v[3] + zz };
      const size_t o = (size_t)(nt * 256 + row) * C_CLS + gc;
      *(f32x4*)&mind[o] = ov;
      f32x4 nv = { -ov[0], -ov[1], -ov[2], -ov[3] };
      *(f32x4*)&logits[o] = nv;
    }
  }
}

// ---------- fallback (fp32) in case ws_size is too small ----------
__global__ void fallback_kernel(const float* __restrict__ z, const float* __restrict__ mu,
                                float* __restrict__ logits, float* __restrict__ mind) {
  const int b = blockIdx.x;
  const int w = threadIdx.x >> 6, l = threadIdx.x & 63;
  const int c = blockIdx.y * 4 + w;
  const float* zr = z + (size_t)b * D_DIM;
  float best = 3.4e38f;
  for (int p = 0; p < 8; ++p) {
    const float* m = mu + ((size_t)c * 8 + p) * D_DIM;
    float s = 0.f;
    for (int d = l; d < D_DIM; d += 64) {
      float df = zr[d] - m[d];
      s = fmaf(df, df, s);
    }
    #pragma unroll
    for (int off = 32; off; off >>= 1) s += __shfl_down(s, off);
    s = __shfl(s, 0);
    best = fminf(best, s);
  }
  if (l == 0) {
    logits[(size_t)b * C_CLS + c] = -best;
    mind[(size_t)b * C_CLS + c] = best;
  }
}

extern "C" void kernel_launch(void* const* d_in, const int* in_sizes, int n_in,
                              void* d_out, int out_size, void* d_ws, size_t ws_size,
                              hipStream_t stream) {
  const float* z  = (const float*)d_in[0];
  const float* mu = (const float*)d_in[1];
  float* logits = (float*)d_out;
  float* mind   = logits + (size_t)B_ROWS * C_CLS;

  const size_t zb_bytes  = (size_t)B_ROWS * D_DIM * 2;
  const size_t mub_bytes = (size_t)NPROTO * D_DIM * 2;
  const size_t need = zb_bytes + mub_bytes + (size_t)B_ROWS * 4 + (size_t)NPROTO * 4;

  if (ws_size >= need) {
    char* p = (char*)d_ws;
    __bf16* zb  = (__bf16*)p; p += zb_bytes;
    __bf16* mub = (__bf16*)p; p += mub_bytes;
    float* z2   = (float*)p;  p += (size_t)B_ROWS * 4;
    float* mu2  = (float*)p;
    prep_rows<<<(B_ROWS + NPROTO) / 4, 256, 0, stream>>>(z, mu, zb, mub, z2, mu2);
    proto_gemm<<<MT * NT, 512, 0, stream>>>(zb, mub, z2, mu2, logits, mind);
  } else {
    dim3 g(B_ROWS, C_CLS / 4);
    fallback_kernel<<<g, 256, 0, stream>>>(z, mu, logits, mind);
  }
}